// Round 3
// baseline (324.799 us; speedup 1.0000x reference)
//
#include <hip/hip_runtime.h>
#include <hip/hip_bf16.h>
#include <stdint.h>

#define HEADS 16
#define HD 64
#define SEQ 2048
#define BATCH 2
#define CDIM 1024
#define MROWS (BATCH*SEQ)   // 4096
#define K3C (3*CDIM)        // 3072
#define ATT_SCALE 0.125f

typedef __bf16 bf16x8 __attribute__((ext_vector_type(8)));
typedef float  f32x4  __attribute__((ext_vector_type(4)));

__device__ __forceinline__ unsigned short f2bf(float f) {
    __hip_bfloat16 h = __float2bfloat16(f);
    return __builtin_bit_cast(unsigned short, h);
}
__device__ __forceinline__ unsigned int pack2bf(float a, float b) {
    return (unsigned int)f2bf(a) | ((unsigned int)f2bf(b) << 16);
}
__device__ __forceinline__ bf16x8 frag(uint4 u) { return __builtin_bit_cast(bf16x8, u); }

// async global->LDS: per-lane global gather -> contiguous LDS (base + lane*16)
__device__ __forceinline__ void async16(const unsigned short* g, unsigned short* lds) {
    __builtin_amdgcn_global_load_lds(
        (const __attribute__((address_space(1))) unsigned int*)g,
        (__attribute__((address_space(3))) unsigned int*)lds, 16, 0, 0);
}

// ---------------- cast / pack kernels ----------------

__global__ void cast_pack_A(const float* __restrict__ q, const float* __restrict__ k,
                            const float* __restrict__ v, unsigned short* __restrict__ A)
{
    const int m = blockIdx.x;
    const int t = threadIdx.x;
    const float* srcs[3] = {q, k, v};
    #pragma unroll
    for (int i = 0; i < 3; ++i) {
        float4 f = *(const float4*)(srcs[i] + (size_t)m*CDIM + t*4);
        ushort4 s;
        s.x = f2bf(f.x); s.y = f2bf(f.y); s.z = f2bf(f.z); s.w = f2bf(f.w);
        *(ushort4*)(A + (size_t)m*K3C + i*CDIM + t*4) = s;
    }
}

__global__ void cast_w(const float* __restrict__ src, unsigned short* __restrict__ dst, int n4)
{
    int idx = blockIdx.x * blockDim.x + threadIdx.x;
    if (idx < n4) {
        float4 f = ((const float4*)src)[idx];
        ushort4 s;
        s.x = f2bf(f.x); s.y = f2bf(f.y); s.z = f2bf(f.z); s.w = f2bf(f.w);
        ((ushort4*)dst)[idx] = s;
    }
}

// ---------------- bf16 GEMM, BK=64 (two BK=32 half-K planes), C[m][n]=sum_k A[m][k]B[n][k]
template<int EPI>
__global__ __launch_bounds__(256, 2)
void gemm_bt(const unsigned short* __restrict__ A, const unsigned short* __restrict__ B,
             int M, int N, int K,
             unsigned short* __restrict__ qh, unsigned short* __restrict__ kh,
             unsigned short* __restrict__ vt,
             const float* __restrict__ bias, float* __restrict__ out)
{
    // layout: [half][128 rows][32 cols] per matrix, half = k0+32*half
    __shared__ __attribute__((aligned(16))) unsigned short As[2*128*32];
    __shared__ __attribute__((aligned(16))) unsigned short Bs[2*128*32];
    const int tid  = threadIdx.x;
    const int wave = tid >> 6;
    const int lane = tid & 63;
    const int l15  = lane & 15;
    const int quad = lane >> 4;
    const int wm = (wave >> 1) * 64;
    const int wn = (wave & 1) * 64;
    const int m0 = blockIdx.x * 128;
    const int n0 = blockIdx.y * 128;

    f32x4 acc[4][4] = {};

    // staging decode: chunk c = t*256 + tid; half=t>>1, row=(t&1)*64 + (tid>>2), col8=(tid&3)*8
    const int srow = tid >> 2;          // wave*16 + lane>>2
    const int sc8  = (tid & 3) * 8;

    for (int k0 = 0; k0 < K; k0 += 64) {
        #pragma unroll
        for (int t = 0; t < 4; ++t) {
            int row  = (t & 1) * 64 + srow;
            int col  = (t >> 1) * 32 + sc8;
            const unsigned short* ga = A + (size_t)(m0 + row)*K + k0 + col;
            const unsigned short* gb = B + (size_t)(n0 + row)*K + k0 + col;
            async16(ga, &As[(t*256 + wave*64)*8]);
            async16(gb, &Bs[(t*256 + wave*64)*8]);
        }
        __syncthreads();
        #pragma unroll
        for (int kk = 0; kk < 2; ++kk) {
            uint4 af[4], bfv[4];
            #pragma unroll
            for (int i = 0; i < 4; ++i) {
                af[i]  = *(const uint4*)&As[kk*4096 + (wm + i*16 + l15)*32 + quad*8];
                bfv[i] = *(const uint4*)&Bs[kk*4096 + (wn + i*16 + l15)*32 + quad*8];
            }
            #pragma unroll
            for (int mi = 0; mi < 4; ++mi)
                #pragma unroll
                for (int ni = 0; ni < 4; ++ni)
                    acc[mi][ni] = __builtin_amdgcn_mfma_f32_16x16x32_bf16(
                        frag(af[mi]), frag(bfv[ni]), acc[mi][ni], 0, 0, 0);
        }
        __syncthreads();
    }

    if constexpr (EPI == 0) {
        #pragma unroll
        for (int mi = 0; mi < 4; ++mi) {
            int row0 = m0 + wm + mi*16 + quad*4;
            int b  = row0 >> 11;
            int nq = row0 & 2047;
            #pragma unroll
            for (int ni = 0; ni < 4; ++ni) {
                int col   = n0 + wn + ni*16 + l15;
                int which = col >> 10;
                int h     = (col >> 6) & 15;
                int d     = col & 63;
                int bh    = b*HEADS + h;
                if (which == 2) {
                    ushort4 pv;
                    pv.x = f2bf(acc[mi][ni][0]);
                    pv.y = f2bf(acc[mi][ni][1]);
                    pv.z = f2bf(acc[mi][ni][2]);
                    pv.w = f2bf(acc[mi][ni][3]);
                    *(ushort4*)&vt[((size_t)bh*HD + d)*SEQ + nq] = pv;
                } else {
                    unsigned short* dst = (which == 0) ? qh : kh;
                    float sc = (which == 0) ? ATT_SCALE : 1.0f;
                    #pragma unroll
                    for (int r = 0; r < 4; ++r)
                        dst[((size_t)bh*SEQ + nq + r)*HD + d] = f2bf(acc[mi][ni][r] * sc);
                }
            }
        }
    } else {
        #pragma unroll
        for (int mi = 0; mi < 4; ++mi) {
            int row0 = m0 + wm + mi*16 + quad*4;
            #pragma unroll
            for (int ni = 0; ni < 4; ++ni) {
                int col  = n0 + wn + ni*16 + l15;
                float bv = bias[col];
                #pragma unroll
                for (int r = 0; r < 4; ++r)
                    out[(size_t)(row0 + r)*N + col] = acc[mi][ni][r] + bv;
            }
        }
    }
}

// ---------------- flash attention, S^T formulation, 32 q per wave ----------------
// Block: 4 waves x 32 q = 128 q. K/V frag reads amortized over 2 q-groups per wave.
__global__ __launch_bounds__(256, 2)
void attention(const unsigned short* __restrict__ qh, const unsigned short* __restrict__ kh,
               const unsigned short* __restrict__ vt, unsigned short* __restrict__ xb)
{
    const int qt = blockIdx.x;          // 0..15 (tiles of 128 q)
    const int h  = blockIdx.y;
    const int b  = blockIdx.z;
    const int bh = b*HEADS + h;
    const int tid  = threadIdx.x;
    const int wave = tid >> 6;
    const int lane = tid & 63;
    const int l15  = lane & 15;
    const int quad = lane >> 4;

    __shared__ __attribute__((aligned(16))) unsigned short Ks[64*72];
    __shared__ __attribute__((aligned(16))) unsigned short Vs[64*72];
    __shared__ __attribute__((aligned(16))) unsigned short Ps[4][2*16*72];

    const unsigned short* Qp = qh + ((size_t)bh*SEQ + qt*128 + wave*32)*HD;
    const unsigned short* Kp = kh + (size_t)bh*SEQ*HD;
    const unsigned short* Vp = vt + (size_t)bh*HD*SEQ;

    // Q B-frags (pre-scaled by 1/8): group g rows g*16+l15
    uint4 qf[2][2];
    #pragma unroll
    for (int g = 0; g < 2; ++g) {
        qf[g][0] = *(const uint4*)(Qp + (size_t)(g*16 + l15)*HD + quad*8);
        qf[g][1] = *(const uint4*)(Qp + (size_t)(g*16 + l15)*HD + 32 + quad*8);
    }

    f32x4 o[2][4] = {};
    float m_s[2] = {-INFINITY, -INFINITY};
    float l_s[2] = {0.f, 0.f};

    unsigned short* Pw = Ps[wave];

    for (int kt = 0; kt < SEQ/64; ++kt) {
        __syncthreads();
        #pragma unroll
        for (int t = 0; t < 2; ++t) {
            int rr = t*32 + (tid >> 3);
            int c8 = (tid & 7) * 8;
            *(uint4*)&Ks[rr*72 + c8] = *(const uint4*)(Kp + ((size_t)(kt*64 + rr))*HD + c8);
            *(uint4*)&Vs[rr*72 + c8] = *(const uint4*)(Vp + (size_t)rr*SEQ + kt*64 + c8);
        }
        __syncthreads();

        // S^T: s[g][st][r] = score(key = kt*64 + st*16 + quad*4 + r, q = g*16+l15)
        f32x4 s[2][4];
        #pragma unroll
        for (int st = 0; st < 4; ++st) {
            uint4 kf0 = *(const uint4*)&Ks[(st*16 + l15)*72 + quad*8];
            uint4 kf1 = *(const uint4*)&Ks[(st*16 + l15)*72 + 32 + quad*8];
            #pragma unroll
            for (int g = 0; g < 2; ++g) {
                f32x4 z = {};
                z = __builtin_amdgcn_mfma_f32_16x16x32_bf16(frag(kf0), frag(qf[g][0]), z, 0, 0, 0);
                z = __builtin_amdgcn_mfma_f32_16x16x32_bf16(frag(kf1), frag(qf[g][1]), z, 0, 0, 0);
                s[g][st] = z;
            }
        }

        #pragma unroll
        for (int g = 0; g < 2; ++g) {
            float mloc = s[g][0][0];
            #pragma unroll
            for (int st = 0; st < 4; ++st)
                #pragma unroll
                for (int r = 0; r < 4; ++r)
                    mloc = fmaxf(mloc, s[g][st][r]);
            mloc = fmaxf(mloc, __shfl_xor(mloc, 16));
            mloc = fmaxf(mloc, __shfl_xor(mloc, 32));

            float mn = fmaxf(m_s[g], mloc);
            float al = __expf(m_s[g] - mn);
            m_s[g] = mn;

            float rs = 0.f;
            float p[4][4];
            #pragma unroll
            for (int st = 0; st < 4; ++st)
                #pragma unroll
                for (int r = 0; r < 4; ++r) { p[st][r] = __expf(s[g][st][r] - mn); rs += p[st][r]; }
            rs += __shfl_xor(rs, 16);
            rs += __shfl_xor(rs, 32);
            l_s[g] = al*l_s[g] + rs;

            #pragma unroll
            for (int st = 0; st < 4; ++st)
                #pragma unroll
                for (int r = 0; r < 4; ++r)
                    o[g][st][r] *= al;

            // P^T -> LDS [q][key], packed b64
            #pragma unroll
            for (int st = 0; st < 4; ++st) {
                uint2 pk;
                pk.x = pack2bf(p[st][0], p[st][1]);
                pk.y = pack2bf(p[st][2], p[st][3]);
                *(uint2*)&Pw[g*1152 + l15*72 + st*16 + quad*4] = pk;
            }
        }
        asm volatile("s_waitcnt lgkmcnt(0)" ::: "memory");

        uint4 pB[2][2];
        #pragma unroll
        for (int g = 0; g < 2; ++g) {
            pB[g][0] = *(const uint4*)&Pw[g*1152 + l15*72 + quad*8];
            pB[g][1] = *(const uint4*)&Pw[g*1152 + l15*72 + 32 + quad*8];
        }

        #pragma unroll
        for (int st = 0; st < 4; ++st) {
            uint4 vf0 = *(const uint4*)&Vs[(st*16 + l15)*72 + quad*8];
            uint4 vf1 = *(const uint4*)&Vs[(st*16 + l15)*72 + 32 + quad*8];
            #pragma unroll
            for (int g = 0; g < 2; ++g) {
                o[g][st] = __builtin_amdgcn_mfma_f32_16x16x32_bf16(frag(vf0), frag(pB[g][0]), o[g][st], 0, 0, 0);
                o[g][st] = __builtin_amdgcn_mfma_f32_16x16x32_bf16(frag(vf1), frag(pB[g][1]), o[g][st], 0, 0, 0);
            }
        }
    }

    // epilogue: o[g] holds out^T (d=st*16+quad*4+r, q=l15). Normalize, transpose via LDS.
    #pragma unroll
    for (int g = 0; g < 2; ++g) {
        float inv = 1.0f / l_s[g];
        #pragma unroll
        for (int st = 0; st < 4; ++st) {
            uint2 pk;
            pk.x = pack2bf(o[g][st][0]*inv, o[g][st][1]*inv);
            pk.y = pack2bf(o[g][st][2]*inv, o[g][st][3]*inv);
            *(uint2*)&Pw[g*1152 + l15*72 + st*16 + quad*4] = pk;
        }
    }
    asm volatile("s_waitcnt lgkmcnt(0)" ::: "memory");

    const int qr = lane >> 2;          // 0..15
    const int dd = (lane & 3) * 16;    // 0,16,32,48
    #pragma unroll
    for (int g = 0; g < 2; ++g) {
        uint4 oa = *(const uint4*)&Pw[g*1152 + qr*72 + dd];
        uint4 ob = *(const uint4*)&Pw[g*1152 + qr*72 + dd + 8];
        const int mrow = b*SEQ + qt*128 + wave*32 + g*16 + qr;
        *(uint4*)&xb[(size_t)mrow*CDIM + h*HD + dd]     = oa;
        *(uint4*)&xb[(size_t)mrow*CDIM + h*HD + dd + 8] = ob;
    }
}

extern "C" void kernel_launch(void* const* d_in, const int* in_sizes, int n_in,
                              void* d_out, int out_size, void* d_ws, size_t ws_size,
                              hipStream_t stream)
{
    const float* q  = (const float*)d_in[0];
    const float* k  = (const float*)d_in[1];
    const float* v  = (const float*)d_in[2];
    const float* Wq = (const float*)d_in[3];
    const float* Wp = (const float*)d_in[4];
    const float* bp = (const float*)d_in[5];
    float* out = (float*)d_out;

    char* p = (char*)d_ws;
    auto carve = [&](size_t bytes) { char* r = p; p += (bytes + 255) & ~(size_t)255; return r; };
    unsigned short* Abuf   = (unsigned short*)carve((size_t)MROWS*K3C*2);
    unsigned short* Wqkvb  = (unsigned short*)carve((size_t)K3C*K3C*2);
    unsigned short* Wprojb = (unsigned short*)carve((size_t)CDIM*CDIM*2);
    unsigned short* qhb    = (unsigned short*)carve((size_t)BATCH*HEADS*SEQ*HD*2);
    unsigned short* khb    = (unsigned short*)carve((size_t)BATCH*HEADS*SEQ*HD*2);
    unsigned short* vtb    = (unsigned short*)carve((size_t)BATCH*HEADS*SEQ*HD*2);
    unsigned short* xbuf   = (unsigned short*)carve((size_t)MROWS*CDIM*2);

    cast_pack_A<<<MROWS, 256, 0, stream>>>(q, k, v, Abuf);
    cast_w<<<(K3C*K3C/4 + 255)/256, 256, 0, stream>>>(Wq, Wqkvb, K3C*K3C/4);
    cast_w<<<(CDIM*CDIM/4 + 255)/256, 256, 0, stream>>>(Wp, Wprojb, CDIM*CDIM/4);

    gemm_bt<0><<<dim3(MROWS/128, K3C/128), 256, 0, stream>>>(
        Abuf, Wqkvb, MROWS, K3C, K3C, qhb, khb, vtb, nullptr, nullptr);

    attention<<<dim3(SEQ/128, HEADS, BATCH), 256, 0, stream>>>(qhb, khb, vtb, xbuf);

    gemm_bt<1><<<dim3(MROWS/128, CDIM/128), 256, 0, stream>>>(
        xbuf, Wprojb, MROWS, CDIM, CDIM, nullptr, nullptr, nullptr, bp, out);
}

// Round 4
// 314.494 us; speedup vs baseline: 1.0328x; 1.0328x over previous
//
#include <hip/hip_runtime.h>
#include <hip/hip_bf16.h>
#include <stdint.h>

#define HEADS 16
#define HD 64
#define SEQ 2048
#define BATCH 2
#define CDIM 1024
#define MROWS (BATCH*SEQ)   // 4096
#define K3C (3*CDIM)        // 3072
#define ATT_SCALE 0.125f

typedef __bf16 bf16x8 __attribute__((ext_vector_type(8)));
typedef float  f32x4  __attribute__((ext_vector_type(4)));

__device__ __forceinline__ unsigned short f2bf(float f) {
    __hip_bfloat16 h = __float2bfloat16(f);
    return __builtin_bit_cast(unsigned short, h);
}
__device__ __forceinline__ unsigned int pack2bf(float a, float b) {
    return (unsigned int)f2bf(a) | ((unsigned int)f2bf(b) << 16);
}
__device__ __forceinline__ bf16x8 frag(uint4 u) { return __builtin_bit_cast(bf16x8, u); }

// async global->LDS: per-lane global gather -> contiguous LDS (base + lane*16)
__device__ __forceinline__ void async16(const unsigned short* g, unsigned short* lds) {
    __builtin_amdgcn_global_load_lds(
        (const __attribute__((address_space(1))) unsigned int*)g,
        (__attribute__((address_space(3))) unsigned int*)lds, 16, 0, 0);
}

// ---------------- fused cast kernel ----------------
// blocks [0,4096): pack one row of q|k|v -> A bf16 [4096][3072]
// blocks [4096,13312): cast W_qkv (9216 blocks x 1024 floats)
// blocks [13312,14336): cast W_proj (1024 blocks x 1024 floats)
__global__ void cast_all(const float* __restrict__ q, const float* __restrict__ k,
                         const float* __restrict__ v, const float* __restrict__ Wq,
                         const float* __restrict__ Wp,
                         unsigned short* __restrict__ A, unsigned short* __restrict__ Wqb,
                         unsigned short* __restrict__ Wpb)
{
    const int bid = blockIdx.x;
    const int t = threadIdx.x;
    if (bid < MROWS) {
        const float* srcs[3] = {q, k, v};
        #pragma unroll
        for (int i = 0; i < 3; ++i) {
            float4 f = *(const float4*)(srcs[i] + (size_t)bid*CDIM + t*4);
            ushort4 s;
            s.x = f2bf(f.x); s.y = f2bf(f.y); s.z = f2bf(f.z); s.w = f2bf(f.w);
            *(ushort4*)(A + (size_t)bid*K3C + i*CDIM + t*4) = s;
        }
    } else if (bid < MROWS + 9216) {
        int idx = (bid - MROWS)*256 + t;
        float4 f = ((const float4*)Wq)[idx];
        ushort4 s;
        s.x = f2bf(f.x); s.y = f2bf(f.y); s.z = f2bf(f.z); s.w = f2bf(f.w);
        ((ushort4*)Wqb)[idx] = s;
    } else {
        int idx = (bid - MROWS - 9216)*256 + t;
        float4 f = ((const float4*)Wp)[idx];
        ushort4 s;
        s.x = f2bf(f.x); s.y = f2bf(f.y); s.z = f2bf(f.z); s.w = f2bf(f.w);
        ((ushort4*)Wpb)[idx] = s;
    }
}

// ---------------- m97-style bf16 GEMM (R2 version, BK=32) ----------------
template<int EPI>
__global__ __launch_bounds__(256, 2)
void gemm_bt(const unsigned short* __restrict__ A, const unsigned short* __restrict__ B,
             int M, int N, int K,
             unsigned short* __restrict__ qh, unsigned short* __restrict__ kh,
             unsigned short* __restrict__ vt,
             const float* __restrict__ bias, float* __restrict__ out)
{
    __shared__ __attribute__((aligned(16))) unsigned short As[128*32];
    __shared__ __attribute__((aligned(16))) unsigned short Bs[128*32];
    const int tid  = threadIdx.x;
    const int wave = tid >> 6;
    const int lane = tid & 63;
    const int l15  = lane & 15;
    const int quad = lane >> 4;
    const int wm = (wave >> 1) * 64;
    const int wn = (wave & 1) * 64;
    const int m0 = blockIdx.x * 128;
    const int n0 = blockIdx.y * 128;

    f32x4 acc[4][4] = {};

    const int srow = tid >> 2;
    const int sc8  = (tid & 3) * 8;

    for (int k0 = 0; k0 < K; k0 += 32) {
        #pragma unroll
        for (int t = 0; t < 2; ++t) {
            int row = t*64 + srow;
            const unsigned short* ga = A + (size_t)(m0 + row)*K + k0 + sc8;
            const unsigned short* gb = B + (size_t)(n0 + row)*K + k0 + sc8;
            async16(ga, &As[(t*256 + wave*64)*8]);
            async16(gb, &Bs[(t*256 + wave*64)*8]);
        }
        __syncthreads();
        uint4 af[4], bfv[4];
        #pragma unroll
        for (int i = 0; i < 4; ++i) {
            af[i]  = *(const uint4*)&As[(wm + i*16 + l15)*32 + quad*8];
            bfv[i] = *(const uint4*)&Bs[(wn + i*16 + l15)*32 + quad*8];
        }
        #pragma unroll
        for (int mi = 0; mi < 4; ++mi)
            #pragma unroll
            for (int ni = 0; ni < 4; ++ni)
                acc[mi][ni] = __builtin_amdgcn_mfma_f32_16x16x32_bf16(
                    frag(af[mi]), frag(bfv[ni]), acc[mi][ni], 0, 0, 0);
        __syncthreads();
    }

    if constexpr (EPI == 0) {
        #pragma unroll
        for (int mi = 0; mi < 4; ++mi) {
            int row0 = m0 + wm + mi*16 + quad*4;
            int b  = row0 >> 11;
            int nq = row0 & 2047;
            #pragma unroll
            for (int ni = 0; ni < 4; ++ni) {
                int col   = n0 + wn + ni*16 + l15;
                int which = col >> 10;
                int h     = (col >> 6) & 15;
                int d     = col & 63;
                int bh    = b*HEADS + h;
                if (which == 2) {
                    ushort4 pv;
                    pv.x = f2bf(acc[mi][ni][0]);
                    pv.y = f2bf(acc[mi][ni][1]);
                    pv.z = f2bf(acc[mi][ni][2]);
                    pv.w = f2bf(acc[mi][ni][3]);
                    *(ushort4*)&vt[((size_t)bh*HD + d)*SEQ + nq] = pv;
                } else {
                    unsigned short* dst = (which == 0) ? qh : kh;
                    float sc = (which == 0) ? ATT_SCALE : 1.0f;
                    #pragma unroll
                    for (int r = 0; r < 4; ++r)
                        dst[((size_t)bh*SEQ + nq + r)*HD + d] = f2bf(acc[mi][ni][r] * sc);
                }
            }
        }
    } else {
        #pragma unroll
        for (int mi = 0; mi < 4; ++mi) {
            int row0 = m0 + wm + mi*16 + quad*4;
            #pragma unroll
            for (int ni = 0; ni < 4; ++ni) {
                int col  = n0 + wn + ni*16 + l15;
                float bv = bias[col];
                #pragma unroll
                for (int r = 0; r < 4; ++r)
                    out[(size_t)(row0 + r)*N + col] = acc[mi][ni][r] + bv;
            }
        }
    }
}

// ---------------- flash attention, S^T form, async double-buffered K/V ----------------
// Grid (SEQ/64, HEADS, BATCH) = 1024 blocks (4 blocks/CU by grid), 16 q per wave.
// K/V staged via global_load_lds with XOR chunk swizzle (16B chunk (r,cc) at pos
// r*8 + (cc^(r&7))), double-buffered; raw s_barrier + s_waitcnt vmcnt(4) keeps
// the next tile's loads in flight across the barrier (no vmcnt(0) drain).
__global__ __launch_bounds__(256, 2)
void attention(const unsigned short* __restrict__ qh, const unsigned short* __restrict__ kh,
               const unsigned short* __restrict__ vt, unsigned short* __restrict__ xb)
{
    const int qt = blockIdx.x;          // 0..31 (tiles of 64 q)
    const int h  = blockIdx.y;
    const int b  = blockIdx.z;
    const int bh = b*HEADS + h;
    const int tid  = threadIdx.x;
    const int wave = tid >> 6;
    const int lane = tid & 63;
    const int l15  = lane & 15;
    const int quad = lane >> 4;

    __shared__ __attribute__((aligned(16))) unsigned short Ks[2][64*64];
    __shared__ __attribute__((aligned(16))) unsigned short Vs[2][64*64];
    __shared__ __attribute__((aligned(16))) unsigned short Ps[4][16*72];

    const unsigned short* Qp = qh + ((size_t)bh*SEQ + qt*64)*HD;
    const unsigned short* Kp = kh + (size_t)bh*SEQ*HD;
    const unsigned short* Vp = vt + (size_t)bh*HD*SEQ;

    // stage K[key][d] and V[d][key] 64x64 tiles for k-tile kt into buffer bufI
    auto stage = [&](int kt, int bufI) {
        #pragma unroll
        for (int t = 0; t < 2; ++t) {
            int c  = t*256 + wave*64 + lane;   // chunk index 0..511
            int r  = c >> 3;
            int cc = (c & 7) ^ (r & 7);
            async16(Kp + (size_t)(kt*64 + r)*HD + cc*8,
                    &Ks[bufI][(t*256 + wave*64)*8]);
            async16(Vp + (size_t)r*SEQ + kt*64 + cc*8,
                    &Vs[bufI][(t*256 + wave*64)*8]);
        }
    };

    // Q B-frags (pre-scaled by 1/8)
    uint4 qf0 = *(const uint4*)(Qp + (size_t)(wave*16 + l15)*HD + quad*8);
    uint4 qf1 = *(const uint4*)(Qp + (size_t)(wave*16 + l15)*HD + 32 + quad*8);

    f32x4 o[4] = {};
    float m_s = -INFINITY, l_s = 0.f;

    unsigned short* Pl = Ps[wave];
    const int x7 = l15 & 7;

    stage(0, 0);

    for (int kt = 0; kt < SEQ/64; ++kt) {
        stage((kt + 1) & 31, (kt + 1) & 1);
        asm volatile("s_waitcnt vmcnt(4)" ::: "memory");
        asm volatile("s_barrier" ::: "memory");

        const unsigned short* Kb = Ks[kt & 1];
        const unsigned short* Vb = Vs[kt & 1];

        // S^T: s[st][r] = score(key = kt*64 + st*16 + quad*4 + r, q = l15)
        f32x4 s[4];
        #pragma unroll
        for (int st = 0; st < 4; ++st) {
            int rb = st*16 + l15;
            uint4 kf0 = *(const uint4*)&Kb[(rb*8 + (quad ^ x7))*8];
            uint4 kf1 = *(const uint4*)&Kb[(rb*8 + ((4 + quad) ^ x7))*8];
            f32x4 z = {};
            z = __builtin_amdgcn_mfma_f32_16x16x32_bf16(frag(kf0), frag(qf0), z, 0, 0, 0);
            z = __builtin_amdgcn_mfma_f32_16x16x32_bf16(frag(kf1), frag(qf1), z, 0, 0, 0);
            s[st] = z;
        }

        // online softmax — one q per lane
        float mloc = s[0][0];
        #pragma unroll
        for (int st = 0; st < 4; ++st)
            #pragma unroll
            for (int r = 0; r < 4; ++r)
                mloc = fmaxf(mloc, s[st][r]);
        mloc = fmaxf(mloc, __shfl_xor(mloc, 16));
        mloc = fmaxf(mloc, __shfl_xor(mloc, 32));

        float mn = fmaxf(m_s, mloc);
        float al = __expf(m_s - mn);
        m_s = mn;

        float p[4][4];
        float rs = 0.f;
        #pragma unroll
        for (int st = 0; st < 4; ++st)
            #pragma unroll
            for (int r = 0; r < 4; ++r) { p[st][r] = __expf(s[st][r] - mn); rs += p[st][r]; }
        rs += __shfl_xor(rs, 16);
        rs += __shfl_xor(rs, 32);
        l_s = al*l_s + rs;

        #pragma unroll
        for (int st = 0; st < 4; ++st)
            #pragma unroll
            for (int r = 0; r < 4; ++r)
                o[st][r] *= al;

        // P^T -> LDS [q][key] (padded stride 72), packed b64
        #pragma unroll
        for (int st = 0; st < 4; ++st) {
            uint2 pk;
            pk.x = pack2bf(p[st][0], p[st][1]);
            pk.y = pack2bf(p[st][2], p[st][3]);
            *(uint2*)&Pl[l15*72 + st*16 + quad*4] = pk;
        }
        asm volatile("s_waitcnt lgkmcnt(0)" ::: "memory");

        uint4 pB0 = *(const uint4*)&Pl[l15*72 + quad*8];
        uint4 pB1 = *(const uint4*)&Pl[l15*72 + 32 + quad*8];

        #pragma unroll
        for (int st = 0; st < 4; ++st) {
            int rb = st*16 + l15;
            uint4 vf0 = *(const uint4*)&Vb[(rb*8 + (quad ^ x7))*8];
            uint4 vf1 = *(const uint4*)&Vb[(rb*8 + ((4 + quad) ^ x7))*8];
            o[st] = __builtin_amdgcn_mfma_f32_16x16x32_bf16(frag(vf0), frag(pB0), o[st], 0, 0, 0);
            o[st] = __builtin_amdgcn_mfma_f32_16x16x32_bf16(frag(vf1), frag(pB1), o[st], 0, 0, 0);
        }

        asm volatile("s_barrier" ::: "memory");
    }

    // epilogue: o holds out^T (d=st*16+quad*4+r, q=l15). Normalize, transpose via LDS.
    float inv = 1.0f / l_s;
    #pragma unroll
    for (int st = 0; st < 4; ++st) {
        uint2 pk;
        pk.x = pack2bf(o[st][0]*inv, o[st][1]*inv);
        pk.y = pack2bf(o[st][2]*inv, o[st][3]*inv);
        *(uint2*)&Pl[l15*72 + st*16 + quad*4] = pk;
    }
    asm volatile("s_waitcnt lgkmcnt(0)" ::: "memory");
    __syncthreads();  // also drains stray prefetch before LDS reuse... (single use; safe)

    const int qr = lane >> 2;          // 0..15
    const int dd = (lane & 3) * 16;    // 0,16,32,48
    uint4 oa = *(const uint4*)&Pl[qr*72 + dd];
    uint4 ob = *(const uint4*)&Pl[qr*72 + dd + 8];
    const int mrow = b*SEQ + qt*64 + wave*16 + qr;
    *(uint4*)&xb[(size_t)mrow*CDIM + h*HD + dd]     = oa;
    *(uint4*)&xb[(size_t)mrow*CDIM + h*HD + dd + 8] = ob;
}

extern "C" void kernel_launch(void* const* d_in, const int* in_sizes, int n_in,
                              void* d_out, int out_size, void* d_ws, size_t ws_size,
                              hipStream_t stream)
{
    const float* q  = (const float*)d_in[0];
    const float* k  = (const float*)d_in[1];
    const float* v  = (const float*)d_in[2];
    const float* Wq = (const float*)d_in[3];
    const float* Wp = (const float*)d_in[4];
    const float* bp = (const float*)d_in[5];
    float* out = (float*)d_out;

    char* p = (char*)d_ws;
    auto carve = [&](size_t bytes) { char* r = p; p += (bytes + 255) & ~(size_t)255; return r; };
    unsigned short* Abuf   = (unsigned short*)carve((size_t)MROWS*K3C*2);
    unsigned short* Wqkvb  = (unsigned short*)carve((size_t)K3C*K3C*2);
    unsigned short* Wprojb = (unsigned short*)carve((size_t)CDIM*CDIM*2);
    unsigned short* qhb    = (unsigned short*)carve((size_t)BATCH*HEADS*SEQ*HD*2);
    unsigned short* khb    = (unsigned short*)carve((size_t)BATCH*HEADS*SEQ*HD*2);
    unsigned short* vtb    = (unsigned short*)carve((size_t)BATCH*HEADS*SEQ*HD*2);
    unsigned short* xbuf   = (unsigned short*)carve((size_t)MROWS*CDIM*2);

    cast_all<<<MROWS + 9216 + 1024, 256, 0, stream>>>(q, k, v, Wq, Wp, Abuf, Wqkvb, Wprojb);

    gemm_bt<0><<<dim3(MROWS/128, K3C/128), 256, 0, stream>>>(
        Abuf, Wqkvb, MROWS, K3C, K3C, qhb, khb, vtb, nullptr, nullptr);

    attention<<<dim3(SEQ/64, HEADS, BATCH), 256, 0, stream>>>(qhb, khb, vtb, xbuf);

    gemm_bt<1><<<dim3(MROWS/128, CDIM/128), 256, 0, stream>>>(
        xbuf, Wprojb, MROWS, CDIM, CDIM, nullptr, nullptr, nullptr, bp, out);
}

// Round 5
// 302.160 us; speedup vs baseline: 1.0749x; 1.0408x over previous
//
#include <hip/hip_runtime.h>
#include <hip/hip_bf16.h>
#include <stdint.h>

#define HEADS 16
#define HD 64
#define SEQ 2048
#define BATCH 2
#define CDIM 1024
#define MROWS (BATCH*SEQ)   // 4096
#define K3C (3*CDIM)        // 3072
// Q prescale: attn scale 1/8 times log2(e), so softmax uses exp2 directly
#define QSCALE 0.1803368801111244f

typedef __bf16 bf16x8 __attribute__((ext_vector_type(8)));
typedef float  f32x4  __attribute__((ext_vector_type(4)));

__device__ __forceinline__ unsigned short f2bf(float f) {
    __hip_bfloat16 h = __float2bfloat16(f);
    return __builtin_bit_cast(unsigned short, h);
}
__device__ __forceinline__ unsigned int pack2bf(float a, float b) {
    return (unsigned int)f2bf(a) | ((unsigned int)f2bf(b) << 16);
}
__device__ __forceinline__ bf16x8 frag(uint4 u) { return __builtin_bit_cast(bf16x8, u); }

// async global->LDS: per-lane global gather -> contiguous LDS (base + lane*16)
__device__ __forceinline__ void async16(const unsigned short* g, unsigned short* lds) {
    __builtin_amdgcn_global_load_lds(
        (const __attribute__((address_space(1))) unsigned int*)g,
        (__attribute__((address_space(3))) unsigned int*)lds, 16, 0, 0);
}

// ---------------- fused cast kernel ----------------
__global__ void cast_all(const float* __restrict__ q, const float* __restrict__ k,
                         const float* __restrict__ v, const float* __restrict__ Wq,
                         const float* __restrict__ Wp,
                         unsigned short* __restrict__ A, unsigned short* __restrict__ Wqb,
                         unsigned short* __restrict__ Wpb)
{
    const int bid = blockIdx.x;
    const int t = threadIdx.x;
    if (bid < MROWS) {
        const float* srcs[3] = {q, k, v};
        #pragma unroll
        for (int i = 0; i < 3; ++i) {
            float4 f = *(const float4*)(srcs[i] + (size_t)bid*CDIM + t*4);
            ushort4 s;
            s.x = f2bf(f.x); s.y = f2bf(f.y); s.z = f2bf(f.z); s.w = f2bf(f.w);
            *(ushort4*)(A + (size_t)bid*K3C + i*CDIM + t*4) = s;
        }
    } else if (bid < MROWS + 9216) {
        int idx = (bid - MROWS)*256 + t;
        float4 f = ((const float4*)Wq)[idx];
        ushort4 s;
        s.x = f2bf(f.x); s.y = f2bf(f.y); s.z = f2bf(f.z); s.w = f2bf(f.w);
        ((ushort4*)Wqb)[idx] = s;
    } else {
        int idx = (bid - MROWS - 9216)*256 + t;
        float4 f = ((const float4*)Wp)[idx];
        ushort4 s;
        s.x = f2bf(f.x); s.y = f2bf(f.y); s.z = f2bf(f.z); s.w = f2bf(f.w);
        ((ushort4*)Wpb)[idx] = s;
    }
}

// ---------------- m97-style bf16 GEMM (BK=32) ----------------
template<int EPI>
__global__ __launch_bounds__(256, 2)
void gemm_bt(const unsigned short* __restrict__ A, const unsigned short* __restrict__ B,
             int M, int N, int K,
             unsigned short* __restrict__ qh, unsigned short* __restrict__ kh,
             unsigned short* __restrict__ vt,
             const float* __restrict__ bias, float* __restrict__ out)
{
    __shared__ __attribute__((aligned(16))) unsigned short As[128*32];
    __shared__ __attribute__((aligned(16))) unsigned short Bs[128*32];
    const int tid  = threadIdx.x;
    const int wave = tid >> 6;
    const int lane = tid & 63;
    const int l15  = lane & 15;
    const int quad = lane >> 4;
    const int wm = (wave >> 1) * 64;
    const int wn = (wave & 1) * 64;
    const int m0 = blockIdx.x * 128;
    const int n0 = blockIdx.y * 128;

    f32x4 acc[4][4] = {};

    const int srow = tid >> 2;
    const int sc8  = (tid & 3) * 8;

    for (int k0 = 0; k0 < K; k0 += 32) {
        #pragma unroll
        for (int t = 0; t < 2; ++t) {
            int row = t*64 + srow;
            const unsigned short* ga = A + (size_t)(m0 + row)*K + k0 + sc8;
            const unsigned short* gb = B + (size_t)(n0 + row)*K + k0 + sc8;
            async16(ga, &As[(t*256 + wave*64)*8]);
            async16(gb, &Bs[(t*256 + wave*64)*8]);
        }
        __syncthreads();
        uint4 af[4], bfv[4];
        #pragma unroll
        for (int i = 0; i < 4; ++i) {
            af[i]  = *(const uint4*)&As[(wm + i*16 + l15)*32 + quad*8];
            bfv[i] = *(const uint4*)&Bs[(wn + i*16 + l15)*32 + quad*8];
        }
        #pragma unroll
        for (int mi = 0; mi < 4; ++mi)
            #pragma unroll
            for (int ni = 0; ni < 4; ++ni)
                acc[mi][ni] = __builtin_amdgcn_mfma_f32_16x16x32_bf16(
                    frag(af[mi]), frag(bfv[ni]), acc[mi][ni], 0, 0, 0);
        __syncthreads();
    }

    if constexpr (EPI == 0) {
        #pragma unroll
        for (int mi = 0; mi < 4; ++mi) {
            int row0 = m0 + wm + mi*16 + quad*4;
            int b  = row0 >> 11;
            int nq = row0 & 2047;
            #pragma unroll
            for (int ni = 0; ni < 4; ++ni) {
                int col   = n0 + wn + ni*16 + l15;
                int which = col >> 10;
                int h     = (col >> 6) & 15;
                int d     = col & 63;
                int bh    = b*HEADS + h;
                if (which == 2) {
                    ushort4 pv;
                    pv.x = f2bf(acc[mi][ni][0]);
                    pv.y = f2bf(acc[mi][ni][1]);
                    pv.z = f2bf(acc[mi][ni][2]);
                    pv.w = f2bf(acc[mi][ni][3]);
                    *(ushort4*)&vt[((size_t)bh*HD + d)*SEQ + nq] = pv;
                } else {
                    unsigned short* dst = (which == 0) ? qh : kh;
                    float sc = (which == 0) ? QSCALE : 1.0f;
                    #pragma unroll
                    for (int r = 0; r < 4; ++r)
                        dst[((size_t)bh*SEQ + nq + r)*HD + d] = f2bf(acc[mi][ni][r] * sc);
                }
            }
        }
    } else {
        #pragma unroll
        for (int mi = 0; mi < 4; ++mi) {
            int row0 = m0 + wm + mi*16 + quad*4;
            #pragma unroll
            for (int ni = 0; ni < 4; ++ni) {
                int col  = n0 + wn + ni*16 + l15;
                float bv = bias[col];
                #pragma unroll
                for (int r = 0; r < 4; ++r)
                    out[(size_t)(row0 + r)*N + col] = acc[mi][ni][r] + bv;
            }
        }
    }
}

// ---------------- flash attention: 32 q/wave + async double-buffered K/V ----------------
// Grid (SEQ/128, HEADS, BATCH) = 512 blocks (2/CU). Each wave: 32 q (2 groups of 16),
// so the 4x-redundant K/V LDS frag reads are amortized over 2x the MFMA work.
// K/V prefetched via global_load_lds (XOR chunk swizzle, unpadded), double-buffered;
// raw s_barrier + s_waitcnt vmcnt(4) keeps next tile's loads in flight (no vmcnt(0) drain).
__global__ __launch_bounds__(256, 2)
void attention(const unsigned short* __restrict__ qh, const unsigned short* __restrict__ kh,
               const unsigned short* __restrict__ vt, unsigned short* __restrict__ xb)
{
    const int qt = blockIdx.x;          // 0..15 (tiles of 128 q)
    const int h  = blockIdx.y;
    const int b  = blockIdx.z;
    const int bh = b*HEADS + h;
    const int tid  = threadIdx.x;
    const int wave = tid >> 6;
    const int lane = tid & 63;
    const int l15  = lane & 15;
    const int quad = lane >> 4;

    __shared__ __attribute__((aligned(16))) unsigned short Ks[2][64*64];
    __shared__ __attribute__((aligned(16))) unsigned short Vs[2][64*64];
    __shared__ __attribute__((aligned(16))) unsigned short Ps[4][2*16*72];

    const unsigned short* Qp = qh + ((size_t)bh*SEQ + qt*128 + wave*32)*HD;
    const unsigned short* Kp = kh + (size_t)bh*SEQ*HD;
    const unsigned short* Vp = vt + (size_t)bh*HD*SEQ;

    // stage K[key][d] and V^T[d][key] 64x64 tiles for k-tile kt into buffer bufI.
    // 16B chunk (row r, col-chunk cc) stored at position r*8 + (cc ^ (r&7)).
    auto stage = [&](int kt, int bufI) {
        #pragma unroll
        for (int t = 0; t < 2; ++t) {
            int c  = t*256 + wave*64 + lane;   // chunk index 0..511
            int r  = c >> 3;
            int cc = (c & 7) ^ (r & 7);
            async16(Kp + (size_t)(kt*64 + r)*HD + cc*8,
                    &Ks[bufI][(t*256 + wave*64)*8]);
            async16(Vp + (size_t)r*SEQ + kt*64 + cc*8,
                    &Vs[bufI][(t*256 + wave*64)*8]);
        }
    };

    stage(0, 0);

    // Q B-frags (pre-scaled by QSCALE): group g rows g*16+l15
    uint4 qf[2][2];
    #pragma unroll
    for (int g = 0; g < 2; ++g) {
        qf[g][0] = *(const uint4*)(Qp + (size_t)(g*16 + l15)*HD + quad*8);
        qf[g][1] = *(const uint4*)(Qp + (size_t)(g*16 + l15)*HD + 32 + quad*8);
    }

    f32x4 o[2][4] = {};
    float m_s[2] = {-INFINITY, -INFINITY};
    float l_s[2] = {0.f, 0.f};

    unsigned short* Pw = Ps[wave];
    const int x7 = l15 & 7;

    for (int kt = 0; kt < SEQ/64; ++kt) {
        stage((kt + 1) & 31, (kt + 1) & 1);
        asm volatile("s_waitcnt vmcnt(4)" ::: "memory");  // tile kt (and Q) landed
        asm volatile("s_barrier" ::: "memory");

        const unsigned short* Kb = Ks[kt & 1];
        const unsigned short* Vb = Vs[kt & 1];

        // S^T: s[g][st][r] = score(key = kt*64 + st*16 + quad*4 + r, q = g*16+l15)
        f32x4 s[2][4];
        #pragma unroll
        for (int st = 0; st < 4; ++st) {
            int rb = st*16 + l15;
            uint4 kf0 = *(const uint4*)&Kb[(rb*8 + (quad ^ x7))*8];
            uint4 kf1 = *(const uint4*)&Kb[(rb*8 + ((4 + quad) ^ x7))*8];
            #pragma unroll
            for (int g = 0; g < 2; ++g) {
                f32x4 z = {};
                z = __builtin_amdgcn_mfma_f32_16x16x32_bf16(frag(kf0), frag(qf[g][0]), z, 0, 0, 0);
                z = __builtin_amdgcn_mfma_f32_16x16x32_bf16(frag(kf1), frag(qf[g][1]), z, 0, 0, 0);
                s[g][st] = z;
            }
        }

        #pragma unroll
        for (int g = 0; g < 2; ++g) {
            float mloc = s[g][0][0];
            #pragma unroll
            for (int st = 0; st < 4; ++st)
                #pragma unroll
                for (int r = 0; r < 4; ++r)
                    mloc = fmaxf(mloc, s[g][st][r]);
            mloc = fmaxf(mloc, __shfl_xor(mloc, 16));
            mloc = fmaxf(mloc, __shfl_xor(mloc, 32));

            float mn = fmaxf(m_s[g], mloc);
            float al = __builtin_amdgcn_exp2f(m_s[g] - mn);
            m_s[g] = mn;

            float rs = 0.f;
            float p[4][4];
            #pragma unroll
            for (int st = 0; st < 4; ++st)
                #pragma unroll
                for (int r = 0; r < 4; ++r) {
                    p[st][r] = __builtin_amdgcn_exp2f(s[g][st][r] - mn);
                    rs += p[st][r];
                }
            rs += __shfl_xor(rs, 16);
            rs += __shfl_xor(rs, 32);
            l_s[g] = al*l_s[g] + rs;

            #pragma unroll
            for (int st = 0; st < 4; ++st)
                #pragma unroll
                for (int r = 0; r < 4; ++r)
                    o[g][st][r] *= al;

            // P^T -> LDS [q][key] (padded stride 72), packed b64
            #pragma unroll
            for (int st = 0; st < 4; ++st) {
                uint2 pk;
                pk.x = pack2bf(p[st][0], p[st][1]);
                pk.y = pack2bf(p[st][2], p[st][3]);
                *(uint2*)&Pw[g*1152 + l15*72 + st*16 + quad*4] = pk;
            }
        }
        asm volatile("s_waitcnt lgkmcnt(0)" ::: "memory");

        uint4 pB[2][2];
        #pragma unroll
        for (int g = 0; g < 2; ++g) {
            pB[g][0] = *(const uint4*)&Pw[g*1152 + l15*72 + quad*8];
            pB[g][1] = *(const uint4*)&Pw[g*1152 + l15*72 + 32 + quad*8];
        }

        #pragma unroll
        for (int st = 0; st < 4; ++st) {
            int rb = st*16 + l15;
            uint4 vf0 = *(const uint4*)&Vb[(rb*8 + (quad ^ x7))*8];
            uint4 vf1 = *(const uint4*)&Vb[(rb*8 + ((4 + quad) ^ x7))*8];
            #pragma unroll
            for (int g = 0; g < 2; ++g) {
                o[g][st] = __builtin_amdgcn_mfma_f32_16x16x32_bf16(frag(vf0), frag(pB[g][0]), o[g][st], 0, 0, 0);
                o[g][st] = __builtin_amdgcn_mfma_f32_16x16x32_bf16(frag(vf1), frag(pB[g][1]), o[g][st], 0, 0, 0);
            }
        }

        asm volatile("s_barrier" ::: "memory");  // all PV reads of buf kt&1 done before overwrite
    }

    // epilogue: o[g] holds out^T (d=st*16+quad*4+r, q=l15). Normalize, transpose via LDS.
    #pragma unroll
    for (int g = 0; g < 2; ++g) {
        float inv = 1.0f / l_s[g];
        #pragma unroll
        for (int st = 0; st < 4; ++st) {
            uint2 pk;
            pk.x = pack2bf(o[g][st][0]*inv, o[g][st][1]*inv);
            pk.y = pack2bf(o[g][st][2]*inv, o[g][st][3]*inv);
            *(uint2*)&Pw[g*1152 + l15*72 + st*16 + quad*4] = pk;
        }
    }
    asm volatile("s_waitcnt lgkmcnt(0)" ::: "memory");

    const int qr = lane >> 2;          // 0..15
    const int dd = (lane & 3) * 16;    // 0,16,32,48
    #pragma unroll
    for (int g = 0; g < 2; ++g) {
        uint4 oa = *(const uint4*)&Pw[g*1152 + qr*72 + dd];
        uint4 ob = *(const uint4*)&Pw[g*1152 + qr*72 + dd + 8];
        const int mrow = b*SEQ + qt*128 + wave*32 + g*16 + qr;
        *(uint4*)&xb[(size_t)mrow*CDIM + h*HD + dd]     = oa;
        *(uint4*)&xb[(size_t)mrow*CDIM + h*HD + dd + 8] = ob;
    }
}

extern "C" void kernel_launch(void* const* d_in, const int* in_sizes, int n_in,
                              void* d_out, int out_size, void* d_ws, size_t ws_size,
                              hipStream_t stream)
{
    const float* q  = (const float*)d_in[0];
    const float* k  = (const float*)d_in[1];
    const float* v  = (const float*)d_in[2];
    const float* Wq = (const float*)d_in[3];
    const float* Wp = (const float*)d_in[4];
    const float* bp = (const float*)d_in[5];
    float* out = (float*)d_out;

    char* p = (char*)d_ws;
    auto carve = [&](size_t bytes) { char* r = p; p += (bytes + 255) & ~(size_t)255; return r; };
    unsigned short* Abuf   = (unsigned short*)carve((size_t)MROWS*K3C*2);
    unsigned short* Wqkvb  = (unsigned short*)carve((size_t)K3C*K3C*2);
    unsigned short* Wprojb = (unsigned short*)carve((size_t)CDIM*CDIM*2);
    unsigned short* qhb    = (unsigned short*)carve((size_t)BATCH*HEADS*SEQ*HD*2);
    unsigned short* khb    = (unsigned short*)carve((size_t)BATCH*HEADS*SEQ*HD*2);
    unsigned short* vtb    = (unsigned short*)carve((size_t)BATCH*HEADS*SEQ*HD*2);
    unsigned short* xbuf   = (unsigned short*)carve((size_t)MROWS*CDIM*2);

    cast_all<<<MROWS + 9216 + 1024, 256, 0, stream>>>(q, k, v, Wq, Wp, Abuf, Wqkvb, Wprojb);

    gemm_bt<0><<<dim3(MROWS/128, K3C/128), 256, 0, stream>>>(
        Abuf, Wqkvb, MROWS, K3C, K3C, qhb, khb, vtb, nullptr, nullptr);

    attention<<<dim3(SEQ/128, HEADS, BATCH), 256, 0, stream>>>(qhb, khb, vtb, xbuf);

    gemm_bt<1><<<dim3(MROWS/128, CDIM/128), 256, 0, stream>>>(
        xbuf, Wprojb, MROWS, CDIM, CDIM, nullptr, nullptr, nullptr, bp, out);
}